// Round 4
// baseline (19297.723 us; speedup 1.0000x reference)
//
#include <hip/hip_runtime.h>
#include <math.h>

// 2-layer LSTM, B=32 T=256 D=512 H=1024, gate order i,j,f,o, forget bias 1.0
// Structure (5 dispatches total):
//   ZX1 = x @ W1[0:512,:]        (sgemm128)
//   lstm_seq(layer1)             (ONE persistent kernel, 256 steps, grid barrier)
//   ZX2 = h1 @ W2[0:1024,:]      (sgemm128)
//   lstm_seq(layer2) -> d_out

#define HSZ 1024
#define GSZ 4096
#define TSZ 256
#define BSZ 32
#define DSZ 512

__device__ __forceinline__ float sigf(float x) { return 1.0f / (1.0f + __expf(-x)); }

// ---------------- fp32 SGEMM: C[M,N] = A[M,K] @ Bm[K,N] ----------------
// BM=BN=128, BK=16, 256 threads, 8x8 per thread.
__global__ __launch_bounds__(256)
void sgemm128(const float* __restrict__ A, const float* __restrict__ Bm,
              float* __restrict__ C, int M, int N, int K) {
  __shared__ float As[16][132];
  __shared__ float Bs[16][132];
  const int tid = threadIdx.x;
  const int m_base = blockIdx.y * 128;
  const int n_base = blockIdx.x * 128;
  const int tm = tid >> 4, tn = tid & 15;
  float acc[8][8];
#pragma unroll
  for (int i = 0; i < 8; ++i)
#pragma unroll
    for (int j = 0; j < 8; ++j) acc[i][j] = 0.0f;

  for (int kt = 0; kt < K; kt += 16) {
#pragma unroll
    for (int i = 0; i < 2; ++i) {
      int q = tid * 2 + i;
      int ar = q >> 2, akq = (q & 3) * 4;
      float4 av = *(const float4*)(A + (size_t)(m_base + ar) * K + kt + akq);
      As[akq + 0][ar] = av.x;
      As[akq + 1][ar] = av.y;
      As[akq + 2][ar] = av.z;
      As[akq + 3][ar] = av.w;
      int bk = q >> 5, bnq = (q & 31) * 4;
      *(float4*)&Bs[bk][bnq] =
          *(const float4*)(Bm + (size_t)(kt + bk) * N + n_base + bnq);
    }
    __syncthreads();
#pragma unroll
    for (int k = 0; k < 16; ++k) {
      float a[8], b[8];
      *(float4*)&a[0] = *(const float4*)&As[k][tm * 8];
      *(float4*)&a[4] = *(const float4*)&As[k][tm * 8 + 4];
      *(float4*)&b[0] = *(const float4*)&Bs[k][tn * 8];
      *(float4*)&b[4] = *(const float4*)&Bs[k][tn * 8 + 4];
#pragma unroll
      for (int i = 0; i < 8; ++i)
#pragma unroll
        for (int j = 0; j < 8; ++j) acc[i][j] = fmaf(a[i], b[j], acc[i][j]);
    }
    __syncthreads();
  }
#pragma unroll
  for (int i = 0; i < 8; ++i) {
    float* cr = C + (size_t)(m_base + tm * 8 + i) * N + n_base + tn * 8;
    *(float4*)cr = make_float4(acc[i][0], acc[i][1], acc[i][2], acc[i][3]);
    *(float4*)(cr + 4) = make_float4(acc[i][4], acc[i][5], acc[i][6], acc[i][7]);
  }
}

// ---------------- persistent recurrent kernel ----------------
// Grid: 256 blocks = 64 jg x 4 bg; block 512 thr = 4 jq x 8 bl x 16 ks.
// One kernel runs all 256 timesteps; grid-wide barrier per step.
// h crosses blocks via coherent (agent-scope atomic) loads/stores so normal
// cached Wh/ZX reads stay L2-resident (no cache-wide acquire fences in loop).
// Co-residency: 256 blocks = 1 block/CU worst case -> barrier cannot deadlock.
__global__ __launch_bounds__(512)
void lstm_seq(const float* __restrict__ Wh,    // [1024][4096]
              const float* __restrict__ ZX,    // [B][T][4096]
              const float* __restrict__ bias,  // [4096]
              float* __restrict__ Hbuf,        // [B][T][1024]  (in+out)
              unsigned int* __restrict__ bar) {
  __shared__ float red[512][17];
  __shared__ float hlds[8][1025];
  __shared__ float cst[8][16];
  const int tid = threadIdx.x;
  const int jq = tid & 3;
  const int bl = (tid >> 2) & 7;
  const int ks = tid >> 5;  // 0..15
  const int bid = blockIdx.x;
  const int jg = bid & 63;
  const int bg = bid >> 6;
  const int j0 = jg * 16 + jq * 4;
  const int b = bg * 8 + bl;

  if (tid < 128) ((float*)cst)[tid] = 0.0f;

  const float* wbase = Wh + (size_t)(ks * 64) * GSZ + j0;
  unsigned int* grpc = bar + (bid >> 5) * 16;   // 8 group counters, 64B apart
  unsigned int* rootc = bar + 8 * 16;
  unsigned int* flag = bar + 9 * 16;
  const int lane6 = tid & 63;
  const int srow = tid >> 6;  // 0..7
  const float* hsrc_base = Hbuf + (size_t)(bg * 8 + srow) * TSZ * HSZ;
  __syncthreads();

  for (int t = 0; t < TSZ; ++t) {
    float acc[16];
#pragma unroll
    for (int q = 0; q < 16; ++q) acc[q] = 0.0f;

    if (t > 0) {
      // stage h[t-1] rows bg*8..bg*8+7 into LDS (coalesced coherent loads)
      const float* hs = hsrc_base + (size_t)(t - 1) * HSZ;
#pragma unroll
      for (int i = 0; i < 16; ++i) {
        hlds[srow][i * 64 + lane6] = __hip_atomic_load(
            hs + i * 64 + lane6, __ATOMIC_RELAXED, __HIP_MEMORY_SCOPE_AGENT);
      }
      __syncthreads();
      const float* hp = &hlds[bl][ks * 64];
#pragma unroll 4
      for (int k = 0; k < 64; ++k) {
        float s = hp[k];
        const float* wr = wbase + (size_t)k * GSZ;
        float4 w0 = *(const float4*)(wr);
        float4 w1 = *(const float4*)(wr + 1024);
        float4 w2 = *(const float4*)(wr + 2048);
        float4 w3 = *(const float4*)(wr + 3072);
        acc[0] = fmaf(s, w0.x, acc[0]);
        acc[1] = fmaf(s, w0.y, acc[1]);
        acc[2] = fmaf(s, w0.z, acc[2]);
        acc[3] = fmaf(s, w0.w, acc[3]);
        acc[4] = fmaf(s, w1.x, acc[4]);
        acc[5] = fmaf(s, w1.y, acc[5]);
        acc[6] = fmaf(s, w1.z, acc[6]);
        acc[7] = fmaf(s, w1.w, acc[7]);
        acc[8] = fmaf(s, w2.x, acc[8]);
        acc[9] = fmaf(s, w2.y, acc[9]);
        acc[10] = fmaf(s, w2.z, acc[10]);
        acc[11] = fmaf(s, w2.w, acc[11]);
        acc[12] = fmaf(s, w3.x, acc[12]);
        acc[13] = fmaf(s, w3.y, acc[13]);
        acc[14] = fmaf(s, w3.z, acc[14]);
        acc[15] = fmaf(s, w3.w, acc[15]);
      }
    }

    // in-block reduction over ks
#pragma unroll
    for (int q = 0; q < 16; ++q) red[tid][q] = acc[q];
    __syncthreads();
    for (int off = 8; off; off >>= 1) {
      if (ks < off) {
#pragma unroll
        for (int q = 0; q < 16; ++q) {
          acc[q] += red[tid + off * 32][q];
          red[tid][q] = acc[q];
        }
      }
      __syncthreads();
    }

    if (ks == 0) {
      const float* zxr = ZX + (size_t)b * TSZ * GSZ + (size_t)t * GSZ;
      float* hrow = Hbuf + (size_t)b * TSZ * HSZ + (size_t)t * HSZ;
#pragma unroll
      for (int jj = 0; jj < 4; ++jj) {
        int j = j0 + jj;
        float zi = acc[0 + jj] + zxr[j] + bias[j];
        float zj = acc[4 + jj] + zxr[j + 1024] + bias[j + 1024];
        float zf = acc[8 + jj] + zxr[j + 2048] + bias[j + 2048];
        float zo = acc[12 + jj] + zxr[j + 3072] + bias[j + 3072];
        float cold = cst[bl][jq * 4 + jj];
        float cn = sigf(zf + 1.0f) * cold + sigf(zi) * tanhf(zj);
        float hn = sigf(zo) * tanhf(cn);
        cst[bl][jq * 4 + jj] = cn;
        __hip_atomic_store(hrow + j, hn, __ATOMIC_RELAXED,
                           __HIP_MEMORY_SCOPE_AGENT);
      }
    }
    __syncthreads();  // drains h stores (vmcnt(0) before s_barrier)

    // hierarchical grid barrier: 8 group counters -> root -> flag (gen = t+1)
    if (tid == 0) {
      asm volatile("" ::: "memory");
      unsigned int old = __hip_atomic_fetch_add(grpc, 1u, __ATOMIC_RELAXED,
                                                __HIP_MEMORY_SCOPE_AGENT);
      if (old == (unsigned int)(32 * (t + 1) - 1)) {
        unsigned int ro = __hip_atomic_fetch_add(rootc, 1u, __ATOMIC_RELAXED,
                                                 __HIP_MEMORY_SCOPE_AGENT);
        if (ro == (unsigned int)(8 * (t + 1) - 1)) {
          __hip_atomic_store(flag, (unsigned int)(t + 1), __ATOMIC_RELAXED,
                             __HIP_MEMORY_SCOPE_AGENT);
        }
      }
      while (__hip_atomic_load(flag, __ATOMIC_RELAXED,
                               __HIP_MEMORY_SCOPE_AGENT) < (unsigned int)(t + 1)) {
        __builtin_amdgcn_s_sleep(1);
      }
      asm volatile("" ::: "memory");
    }
    __syncthreads();
  }
}

extern "C" void kernel_launch(void* const* d_in, const int* in_sizes, int n_in,
                              void* d_out, int out_size, void* d_ws, size_t ws_size,
                              hipStream_t stream) {
  const float* x  = (const float*)d_in[0];  // [32,256,512]
  const float* W1 = (const float*)d_in[1];  // [1536,4096]
  const float* b1 = (const float*)d_in[2];  // [4096]
  const float* W2 = (const float*)d_in[3];  // [2048,4096]
  const float* b2 = (const float*)d_in[4];  // [4096]
  float* out = (float*)d_out;               // [32,256,1024]

  unsigned int* bar1 = (unsigned int*)d_ws;        // 256 uints
  unsigned int* bar2 = bar1 + 256;                 // 256 uints
  float* H1buf = (float*)(bar2 + 256);             // [B,T,H]
  float* ZX    = H1buf + (size_t)BSZ * TSZ * HSZ;  // [B*T,4096]

  hipMemsetAsync(bar1, 0, 512 * sizeof(unsigned int), stream);

  dim3 gemm_grid(GSZ / 128, (BSZ * TSZ) / 128);  // (32, 64)

  // Layer 1
  sgemm128<<<gemm_grid, 256, 0, stream>>>(x, W1, ZX, BSZ * TSZ, GSZ, DSZ);
  lstm_seq<<<256, 512, 0, stream>>>(W1 + (size_t)DSZ * GSZ, ZX, b1, H1buf, bar1);

  // Layer 2
  sgemm128<<<gemm_grid, 256, 0, stream>>>(H1buf, W2, ZX, BSZ * TSZ, GSZ, HSZ);
  lstm_seq<<<256, 512, 0, stream>>>(W2 + (size_t)HSZ * GSZ, ZX, b2, out, bar2);
}

// Round 5
// 9025.901 us; speedup vs baseline: 2.1380x; 2.1380x over previous
//
#include <hip/hip_runtime.h>
#include <math.h>

// 2-layer LSTM, B=32 T=256 D=512 H=1024, gate order i,j,f,o, forget bias 1.0
// 5 dispatches: sgemm(ZX1) -> lstm_seq(L1) -> sgemm(ZX2) -> lstm_seq(L2)
// lstm_seq: persistent, grid barrier per step.
//   Block = (bg: 8 b-rows) x (jg: 16 j-cols x 4 gates), all 1024 k.
//   Thread (jq,bh,ks) = 4 b x 2 j x 4 g x 32 k -> 8x register reuse of Wh.
//   h transport: producer agent-scope store (write-through, no L2 alloc),
//   consumer PLAIN cached float4 loads (fresh addresses each t; dispatch
//   acquire killed stale lines; barrier orders store->load).

#define HSZ 1024
#define GSZ 4096
#define TSZ 256
#define BSZ 32
#define DSZ 512

__device__ __forceinline__ float sigf(float x) { return 1.0f / (1.0f + __expf(-x)); }

// ---------------- fp32 SGEMM: C[M,N] = A[M,K] @ Bm[K,N] ----------------
__global__ __launch_bounds__(256)
void sgemm128(const float* __restrict__ A, const float* __restrict__ Bm,
              float* __restrict__ C, int M, int N, int K) {
  __shared__ float As[16][132];
  __shared__ float Bs[16][132];
  const int tid = threadIdx.x;
  const int m_base = blockIdx.y * 128;
  const int n_base = blockIdx.x * 128;
  const int tm = tid >> 4, tn = tid & 15;
  float acc[8][8];
#pragma unroll
  for (int i = 0; i < 8; ++i)
#pragma unroll
    for (int j = 0; j < 8; ++j) acc[i][j] = 0.0f;

  for (int kt = 0; kt < K; kt += 16) {
#pragma unroll
    for (int i = 0; i < 2; ++i) {
      int q = tid * 2 + i;
      int ar = q >> 2, akq = (q & 3) * 4;
      float4 av = *(const float4*)(A + (size_t)(m_base + ar) * K + kt + akq);
      As[akq + 0][ar] = av.x;
      As[akq + 1][ar] = av.y;
      As[akq + 2][ar] = av.z;
      As[akq + 3][ar] = av.w;
      int bk = q >> 5, bnq = (q & 31) * 4;
      *(float4*)&Bs[bk][bnq] =
          *(const float4*)(Bm + (size_t)(kt + bk) * N + n_base + bnq);
    }
    __syncthreads();
#pragma unroll
    for (int k = 0; k < 16; ++k) {
      float a[8], b[8];
      *(float4*)&a[0] = *(const float4*)&As[k][tm * 8];
      *(float4*)&a[4] = *(const float4*)&As[k][tm * 8 + 4];
      *(float4*)&b[0] = *(const float4*)&Bs[k][tn * 8];
      *(float4*)&b[4] = *(const float4*)&Bs[k][tn * 8 + 4];
#pragma unroll
      for (int i = 0; i < 8; ++i)
#pragma unroll
        for (int j = 0; j < 8; ++j) acc[i][j] = fmaf(a[i], b[j], acc[i][j]);
    }
    __syncthreads();
  }
#pragma unroll
  for (int i = 0; i < 8; ++i) {
    float* cr = C + (size_t)(m_base + tm * 8 + i) * N + n_base + tn * 8;
    *(float4*)cr = make_float4(acc[i][0], acc[i][1], acc[i][2], acc[i][3]);
    *(float4*)(cr + 4) = make_float4(acc[i][4], acc[i][5], acc[i][6], acc[i][7]);
  }
}

// ---------------- persistent recurrent kernel ----------------
__global__ __launch_bounds__(512, 1)
void lstm_seq(const float* __restrict__ Wh,    // [1024][4096]
              const float* __restrict__ ZX,    // [B][T][4096]
              const float* __restrict__ bias,  // [4096]
              float* __restrict__ Hbuf,        // [B][T][1024]  (in+out)
              unsigned int* __restrict__ bar) {
  __shared__ float hl[8 * 1024];     // h[t-1], XOR-swizzled (bits [6:4] ^= (b^(k>>5))&7)
  __shared__ float P[32 * 516 + 12]; // reduce: idx = ks*516 + b*64 + jl*4 + g (ks-pad +4)
  __shared__ float cst[8][16];       // c state per (b, jl)

  const int tid = threadIdx.x;
  const int jq = tid & 7;         // 2 j-cols: jl = jq*2 + {0,1}
  const int bh = (tid >> 3) & 1;  // 4 b-rows: b = bh*4 + {0..3}
  const int ks = tid >> 4;        // 0..31, k-slice [ks*32, ks*32+32)
  const int bid = blockIdx.x;
  const int jg = bid & 63;
  const int bg = bid >> 6;
  const int jg16 = jg * 16;
  const int bg8 = bg * 8;
  const int bh4 = bh * 4;
  const int j0 = jg16 + jq * 2;

  if (tid < 128) ((float*)cst)[tid] = 0.0f;

  unsigned int* grpc = bar + (bid >> 5) * 16;  // 8 group counters, 64B apart
  unsigned int* rootc = bar + 8 * 16;
  unsigned int* flag = bar + 9 * 16;

  // per-thread LDS read bases for the dot loop: addr = base[bb] + ((c8 ^ xb[bb])<<4)
  unsigned rb[4];
  unsigned xb[4];
#pragma unroll
  for (int bb = 0; bb < 4; ++bb) {
    int b = bh4 + bb;
    rb[bb] = ((unsigned)b << 12) + ((unsigned)ks << 7);
    xb[bb] = (unsigned)((b ^ ks) & 7);
  }
  const float* wkbase = Wh + (size_t)ks * 32 * GSZ + j0;
  __syncthreads();

  for (int t = 0; t < TSZ; ++t) {
    float acc[4][2][4];
#pragma unroll
    for (int bb = 0; bb < 4; ++bb)
#pragma unroll
      for (int jj = 0; jj < 2; ++jj)
#pragma unroll
        for (int g = 0; g < 4; ++g) acc[bb][jj][g] = 0.0f;

    if (t > 0) {
      // stage h[t-1] rows bg8..bg8+7 into swizzled LDS (plain cached loads)
#pragma unroll
      for (int i = 0; i < 4; ++i) {
        int f4 = i * 512 + tid;  // float4 idx in [0,2048)
        int b_l = f4 >> 8;       // 0..7
        int kf4 = f4 & 255;      // float4 within row
        float4 v = *(const float4*)(Hbuf + (size_t)(bg8 + b_l) * TSZ * HSZ +
                                    (size_t)(t - 1) * HSZ + (kf4 << 2));
        unsigned xv = (unsigned)((b_l ^ (kf4 >> 3)) & 7);
        *(float4*)((char*)hl + (((unsigned)f4 ^ xv) << 4)) = v;
      }
      __syncthreads();

      // dot: acc[bb][jj][g] += h[b][k] * Wh[k][j0+jj + g*1024], k in slice
#pragma unroll 2
      for (int c8 = 0; c8 < 8; ++c8) {
        float4 h4[4];
#pragma unroll
        for (int bb = 0; bb < 4; ++bb)
          h4[bb] = *(const float4*)((const char*)hl +
                                    (rb[bb] + (((unsigned)c8 ^ xb[bb]) << 4)));
        const float* wk = wkbase + (size_t)(c8 * 4) * GSZ;
#pragma unroll
        for (int cc = 0; cc < 4; ++cc) {
          const float* wr = wk + (size_t)cc * GSZ;
          float2 w0 = *(const float2*)(wr);
          float2 w1 = *(const float2*)(wr + 1024);
          float2 w2 = *(const float2*)(wr + 2048);
          float2 w3 = *(const float2*)(wr + 3072);
          float hc[4];
#pragma unroll
          for (int bb = 0; bb < 4; ++bb) {
            hc[bb] = (cc == 0) ? h4[bb].x
                   : (cc == 1) ? h4[bb].y
                   : (cc == 2) ? h4[bb].z
                               : h4[bb].w;
          }
#pragma unroll
          for (int bb = 0; bb < 4; ++bb) {
            acc[bb][0][0] = fmaf(hc[bb], w0.x, acc[bb][0][0]);
            acc[bb][1][0] = fmaf(hc[bb], w0.y, acc[bb][1][0]);
            acc[bb][0][1] = fmaf(hc[bb], w1.x, acc[bb][0][1]);
            acc[bb][1][1] = fmaf(hc[bb], w1.y, acc[bb][1][1]);
            acc[bb][0][2] = fmaf(hc[bb], w2.x, acc[bb][0][2]);
            acc[bb][1][2] = fmaf(hc[bb], w2.y, acc[bb][1][2]);
            acc[bb][0][3] = fmaf(hc[bb], w3.x, acc[bb][0][3]);
            acc[bb][1][3] = fmaf(hc[bb], w3.y, acc[bb][1][3]);
          }
        }
      }
    }

    // write partials to P and reduce over the 32 k-slices
#pragma unroll
    for (int bb = 0; bb < 4; ++bb)
#pragma unroll
      for (int jj = 0; jj < 2; ++jj) {
        int b = bh4 + bb;
        int jl = (jq << 1) + jj;
        *(float4*)&P[ks * 516 + b * 64 + jl * 4] =
            make_float4(acc[bb][jj][0], acc[bb][jj][1], acc[bb][jj][2],
                        acc[bb][jj][3]);
      }
    __syncthreads();

    if (tid < 128) {
      int b = tid >> 4, jl = tid & 15;
      float sx = 0.f, sy = 0.f, sz = 0.f, sw = 0.f;
#pragma unroll
      for (int k2 = 0; k2 < 32; ++k2) {
        float4 p = *(const float4*)&P[k2 * 516 + b * 64 + jl * 4];
        sx += p.x; sy += p.y; sz += p.z; sw += p.w;
      }
      int j = jg16 + jl;
      const float* zxr = ZX + ((size_t)(bg8 + b) * TSZ + t) * GSZ;
      float zi = sx + zxr[j] + bias[j];
      float zj = sy + zxr[j + 1024] + bias[j + 1024];
      float zf = sz + zxr[j + 2048] + bias[j + 2048];
      float zo = sw + zxr[j + 3072] + bias[j + 3072];
      float cold = cst[b][jl];
      float cn = sigf(zf + 1.0f) * cold + sigf(zi) * tanhf(zj);
      float hn = sigf(zo) * tanhf(cn);
      cst[b][jl] = cn;
      // write-through to coherence point; no L2 allocation anywhere
      __hip_atomic_store(Hbuf + (size_t)(bg8 + b) * TSZ * HSZ +
                             (size_t)t * HSZ + j,
                         hn, __ATOMIC_RELAXED, __HIP_MEMORY_SCOPE_AGENT);
    }
    __syncthreads();  // drains h stores (vmcnt(0) before s_barrier)

    // hierarchical grid barrier (gen = t+1)
    if (tid == 0) {
      asm volatile("" ::: "memory");
      unsigned int old = __hip_atomic_fetch_add(grpc, 1u, __ATOMIC_RELAXED,
                                                __HIP_MEMORY_SCOPE_AGENT);
      if (old == (unsigned int)(32 * (t + 1) - 1)) {
        unsigned int ro = __hip_atomic_fetch_add(rootc, 1u, __ATOMIC_RELAXED,
                                                 __HIP_MEMORY_SCOPE_AGENT);
        if (ro == (unsigned int)(8 * (t + 1) - 1)) {
          __hip_atomic_store(flag, (unsigned int)(t + 1), __ATOMIC_RELAXED,
                             __HIP_MEMORY_SCOPE_AGENT);
        }
      }
      while (__hip_atomic_load(flag, __ATOMIC_RELAXED,
                               __HIP_MEMORY_SCOPE_AGENT) <
             (unsigned int)(t + 1)) {
        __builtin_amdgcn_s_sleep(1);
      }
      asm volatile("" ::: "memory");
    }
    __syncthreads();
  }
}

extern "C" void kernel_launch(void* const* d_in, const int* in_sizes, int n_in,
                              void* d_out, int out_size, void* d_ws, size_t ws_size,
                              hipStream_t stream) {
  const float* x  = (const float*)d_in[0];  // [32,256,512]
  const float* W1 = (const float*)d_in[1];  // [1536,4096]
  const float* b1 = (const float*)d_in[2];  // [4096]
  const float* W2 = (const float*)d_in[3];  // [2048,4096]
  const float* b2 = (const float*)d_in[4];  // [4096]
  float* out = (float*)d_out;               // [32,256,1024]

  unsigned int* bar1 = (unsigned int*)d_ws;        // 256 uints
  unsigned int* bar2 = bar1 + 256;                 // 256 uints
  float* H1buf = (float*)(bar2 + 256);             // [B,T,H]
  float* ZX    = H1buf + (size_t)BSZ * TSZ * HSZ;  // [B*T,4096]

  hipMemsetAsync(bar1, 0, 512 * sizeof(unsigned int), stream);

  dim3 gemm_grid(GSZ / 128, (BSZ * TSZ) / 128);  // (32, 64)

  // Layer 1
  sgemm128<<<gemm_grid, 256, 0, stream>>>(x, W1, ZX, BSZ * TSZ, GSZ, DSZ);
  lstm_seq<<<256, 512, 0, stream>>>(W1 + (size_t)DSZ * GSZ, ZX, b1, H1buf, bar1);

  // Layer 2
  sgemm128<<<gemm_grid, 256, 0, stream>>>(H1buf, W2, ZX, BSZ * TSZ, GSZ, HSZ);
  lstm_seq<<<256, 512, 0, stream>>>(W2 + (size_t)HSZ * GSZ, ZX, b2, out, bar2);
}